// Round 2
// baseline (970.592 us; speedup 1.0000x reference)
//
#include <hip/hip_runtime.h>
#include <hip/hip_bf16.h>
#include <stdint.h>

#define T_TOKENS 2048
#define HID_DIM 1024
#define INTER 3584
#define NEXP 8

typedef float f32x4 __attribute__((ext_vector_type(4)));
typedef short short8 __attribute__((ext_vector_type(8)));
typedef unsigned short ushort8 __attribute__((ext_vector_type(8)));

#define AS1 __attribute__((address_space(1)))
#define AS3 __attribute__((address_space(3)))

__device__ __forceinline__ void gload_lds16(const void* g, void* l) {
    __builtin_amdgcn_global_load_lds((AS1 void*)g, (AS3 void*)l, 16, 0, 0);
}

__device__ __forceinline__ f32x4 mfma16(short8 a, short8 b, f32x4 c) {
    return __builtin_amdgcn_mfma_f32_16x16x32_bf16(a, b, c, 0, 0, 0);
}

__device__ __forceinline__ unsigned short f2bf(float f) {
    union { __hip_bfloat16 h; unsigned short u; } cv;
    cv.h = __float2bfloat16(f);
    return cv.u;
}

__device__ __forceinline__ ushort8 cvt8(float4 v0, float4 v1) {
    ushort8 u;
    u[0] = f2bf(v0.x); u[1] = f2bf(v0.y); u[2] = f2bf(v0.z); u[3] = f2bf(v0.w);
    u[4] = f2bf(v1.x); u[5] = f2bf(v1.y); u[6] = f2bf(v1.z); u[7] = f2bf(v1.w);
    return u;
}

// ---------------- weight fp32 -> bf16 pre-conversion (once per launch) ----------------
__global__ __launch_bounds__(256) void cvt_k(const float* __restrict__ w1, const float* __restrict__ w2,
                                             const float* __restrict__ w3, unsigned short* __restrict__ w1b,
                                             unsigned short* __restrict__ w2b, unsigned short* __restrict__ w3b) {
    const float* src;
    unsigned short* dst;
    if (blockIdx.z == 0) { src = w1; dst = w1b; }
    else if (blockIdx.z == 1) { src = w2; dst = w2b; }
    else { src = w3; dst = w3b; }
    const size_t N = (size_t)NEXP * INTER * HID_DIM;  // 29,360,128 (same for all 3)
    size_t i = ((size_t)blockIdx.x * 256 + threadIdx.x) * 8;
    size_t stride = (size_t)gridDim.x * 256 * 8;
    for (; i < N; i += stride) {
        float4 v0 = *reinterpret_cast<const float4*>(src + i);
        float4 v1 = *reinterpret_cast<const float4*>(src + i + 4);
        *reinterpret_cast<ushort8*>(dst + i) = cvt8(v0, v1);
    }
}

// ---------------- router: logits (fp32 exact), top-2, counts; X -> bf16 ----------------
__global__ void router_k(const float* __restrict__ x, const float* __restrict__ gw,
                         unsigned short* __restrict__ xb,
                         int* __restrict__ topk_e, float* __restrict__ topk_w,
                         int* __restrict__ ctl) {
    int lane = threadIdx.x & 63;
    int wid = threadIdx.x >> 6;
    int t = blockIdx.x * 4 + wid;
    const float* xr = x + (size_t)t * HID_DIM;

    float acc[NEXP];
#pragma unroll
    for (int e = 0; e < NEXP; ++e) acc[e] = 0.f;

#pragma unroll
    for (int j = 0; j < 4; ++j) {
        int c = j * 256 + lane * 4;
        float4 v = *reinterpret_cast<const float4*>(xr + c);
        ushort4 b;
        b.x = f2bf(v.x); b.y = f2bf(v.y); b.z = f2bf(v.z); b.w = f2bf(v.w);
        *reinterpret_cast<ushort4*>(xb + (size_t)t * HID_DIM + c) = b;
#pragma unroll
        for (int e = 0; e < NEXP; ++e) {
            float4 g = *reinterpret_cast<const float4*>(gw + e * HID_DIM + c);
            acc[e] += v.x * g.x + v.y * g.y + v.z * g.z + v.w * g.w;
        }
    }
#pragma unroll
    for (int off = 32; off > 0; off >>= 1)
#pragma unroll
        for (int e = 0; e < NEXP; ++e) acc[e] += __shfl_xor(acc[e], off, 64);

    if (lane == 0) {
        int e0 = 0;
#pragma unroll
        for (int e = 1; e < NEXP; ++e) if (acc[e] > acc[e0]) e0 = e;
        int e1 = -1;
        float b1 = 0.f;
#pragma unroll
        for (int e = 0; e < NEXP; ++e) {
            if (e == e0) continue;
            if (e1 < 0 || acc[e] > b1) { e1 = e; b1 = acc[e]; }
        }
        float p1 = __expf(b1 - acc[e0]);   // renormalized top-2: softmax denom cancels
        float s = 1.f + p1;
        topk_e[2 * t] = e0; topk_e[2 * t + 1] = e1;
        topk_w[2 * t] = 1.f / s; topk_w[2 * t + 1] = p1 / s;
        atomicAdd(&ctl[e0], 1);
        atomicAdd(&ctl[e1], 1);
    }
}

// ctl layout (ints): [0..8) counts, [16..24) cursors, [32..40) offsets
__global__ void prefix_k(int* __restrict__ ctl) {
    if (threadIdx.x == 0) {
        int r = 0;
        for (int e = 0; e < NEXP; ++e) {
            ctl[32 + e] = r;
            r += ctl[e];
            ctl[16 + e] = 0;
        }
    }
}

__global__ void scatter_k(const int* __restrict__ topk_e, const float* __restrict__ topk_w,
                          int* __restrict__ ctl, int* __restrict__ perm_token,
                          float* __restrict__ perm_gate) {
    int t = blockIdx.x * 256 + threadIdx.x;
    if (t >= T_TOKENS) return;
#pragma unroll
    for (int k = 0; k < 2; ++k) {
        int e = topk_e[2 * t + k];
        int p = ctl[32 + e] + atomicAdd(&ctl[16 + e], 1);
        perm_token[p] = t;
        perm_gate[p] = topk_w[2 * t + k];
    }
}

// ---------------- GEMM1: hid = silu(Xg @ w1^T) * (Xg @ w3^T), gathered rows ----------------
// BM=128, BN=64 (x2 matrices), BK=64. 4 waves 2x2; wave = 64 rows x 32 cols per matrix.
// All staging via global_load_lds width-16 from bf16 sources. LDS 32 KB.
__global__ __launch_bounds__(256) void gemm1_k(
    const unsigned short* __restrict__ xb,
    const unsigned short* __restrict__ w1b, const unsigned short* __restrict__ w3b,
    const int* __restrict__ ctl, const int* __restrict__ perm_token,
    unsigned short* __restrict__ hid) {
    int e = blockIdx.z;
    int cnt = ctl[e];
    int tm = blockIdx.x;
    if (tm * 128 >= cnt) return;
    int off = ctl[32 + e];
    int cb = blockIdx.y * 64;

    __shared__ __attribute__((aligned(16))) unsigned short A_l[8 * 128 * 8];  // [kb][row][8] 16KB
    __shared__ __attribute__((aligned(16))) unsigned short B1_l[8 * 64 * 8];  // [kb][col][8] 8KB
    __shared__ __attribute__((aligned(16))) unsigned short B3_l[8 * 64 * 8];

    int tid = threadIdx.x;
    int lane = tid & 63;
    int wid = tid >> 6;
    int wr = wid >> 1, wc = wid & 1;

    // A staging: row = tid&127 (fixed per thread), kb = 2r + (tid>>7), r=0..3
    int arow = tid & 127;
    int kbA = tid >> 7;
    int grow = tm * 128 + arow;
    int tok = (grow < cnt) ? perm_token[off + grow] : 0;
    const unsigned short* asrc = xb + (size_t)tok * HID_DIM;

    // B staging: col = tid&63 (fixed), kb = 4r + (tid>>6), r=0..1
    int bcol = tid & 63;
    int kbB = tid >> 6;
    const unsigned short* b1s = w1b + ((size_t)e * INTER + cb + bcol) * HID_DIM;
    const unsigned short* b3s = w3b + ((size_t)e * INTER + cb + bcol) * HID_DIM;

    f32x4 acc1[4][2], acc3[4][2];
#pragma unroll
    for (int i = 0; i < 4; ++i)
#pragma unroll
        for (int j = 0; j < 2; ++j) { acc1[i][j] = 0.f; acc3[i][j] = 0.f; }

    int q = lane >> 4, rr = lane & 15;

    for (int k0 = 0; k0 < HID_DIM; k0 += 64) {
#pragma unroll
        for (int r = 0; r < 4; ++r)
            gload_lds16(asrc + k0 + (2 * r + kbA) * 8, A_l + ((2 * r + kbA) * 128 + arow) * 8);
#pragma unroll
        for (int r = 0; r < 2; ++r) {
            gload_lds16(b1s + k0 + (4 * r + kbB) * 8, B1_l + ((4 * r + kbB) * 64 + bcol) * 8);
            gload_lds16(b3s + k0 + (4 * r + kbB) * 8, B3_l + ((4 * r + kbB) * 64 + bcol) * 8);
        }
        __syncthreads();
#pragma unroll
        for (int kk = 0; kk < 2; ++kk) {
            short8 a[4], b1v[2], b3v[2];
            const unsigned short* abase = A_l + (size_t)((kk * 4 + q) * 128 + wr * 64 + rr) * 8;
#pragma unroll
            for (int i = 0; i < 4; ++i) a[i] = *reinterpret_cast<const short8*>(abase + i * 16 * 8);
            const unsigned short* b1base = B1_l + (size_t)((kk * 4 + q) * 64 + wc * 32 + rr) * 8;
            const unsigned short* b3base = B3_l + (size_t)((kk * 4 + q) * 64 + wc * 32 + rr) * 8;
#pragma unroll
            for (int j = 0; j < 2; ++j) {
                b1v[j] = *reinterpret_cast<const short8*>(b1base + j * 16 * 8);
                b3v[j] = *reinterpret_cast<const short8*>(b3base + j * 16 * 8);
            }
#pragma unroll
            for (int i = 0; i < 4; ++i)
#pragma unroll
                for (int j = 0; j < 2; ++j) {
                    acc1[i][j] = mfma16(a[i], b1v[j], acc1[i][j]);
                    acc3[i][j] = mfma16(a[i], b3v[j], acc3[i][j]);
                }
        }
        __syncthreads();
    }

    // epilogue: silu(g) * u -> bf16 hid rows (permuted order)
    int rbase = tm * 128 + wr * 64 + q * 4;
    int fbase = cb + wc * 32 + rr;
#pragma unroll
    for (int i = 0; i < 4; ++i) {
#pragma unroll
        for (int r = 0; r < 4; ++r) {
            int grow2 = rbase + i * 16 + r;
            if (grow2 < cnt) {
                size_t hrow = (size_t)(off + grow2) * INTER;
#pragma unroll
                for (int j = 0; j < 2; ++j) {
                    float g = acc1[i][j][r];
                    float u = acc3[i][j][r];
                    float h = (g / (1.f + __expf(-g))) * u;
                    hid[hrow + fbase + j * 16] = f2bf(h);
                }
            }
        }
    }
}

// ---------------- GEMM2: out[tok] += gate * (hid @ w2^T), BM=128 BN=128 BK=64 ----------------
__global__ __launch_bounds__(256) void gemm2_k(
    const unsigned short* __restrict__ hid, const unsigned short* __restrict__ w2b,
    const int* __restrict__ ctl, const int* __restrict__ perm_token,
    const float* __restrict__ perm_gate, float* __restrict__ out) {
    int e = blockIdx.z;
    int cnt = ctl[e];
    int tm = blockIdx.x;
    if (tm * 128 >= cnt) return;
    int off = ctl[32 + e];
    int cb = blockIdx.y * 128;

    __shared__ __attribute__((aligned(16))) unsigned short A_l[8 * 128 * 8]; // 16KB
    __shared__ __attribute__((aligned(16))) unsigned short B_l[8 * 128 * 8]; // 16KB

    int tid = threadIdx.x;
    int lane = tid & 63;
    int wid = tid >> 6;
    int wr = wid >> 1, wc = wid & 1;

    int arow = tid & 127;
    int kbA = tid >> 7;
    int ap = off + tm * 128 + arow;
    if (ap > T_TOKENS * 2 - 1) ap = T_TOKENS * 2 - 1;  // clamp; garbage rows discarded
    const unsigned short* asrc = hid + (size_t)ap * INTER;

    const unsigned short* bs = w2b + ((size_t)e * HID_DIM + cb + arow) * INTER;

    f32x4 acc[4][4];
#pragma unroll
    for (int i = 0; i < 4; ++i)
#pragma unroll
        for (int j = 0; j < 4; ++j) acc[i][j] = 0.f;

    int q = lane >> 4, rr = lane & 15;

    for (int k0 = 0; k0 < INTER; k0 += 64) {
#pragma unroll
        for (int r = 0; r < 4; ++r) {
            gload_lds16(asrc + k0 + (2 * r + kbA) * 8, A_l + ((2 * r + kbA) * 128 + arow) * 8);
            gload_lds16(bs + k0 + (2 * r + kbA) * 8, B_l + ((2 * r + kbA) * 128 + arow) * 8);
        }
        __syncthreads();
#pragma unroll
        for (int kk = 0; kk < 2; ++kk) {
            short8 a[4], b[4];
            const unsigned short* abase = A_l + (size_t)((kk * 4 + q) * 128 + wr * 64 + rr) * 8;
            const unsigned short* bbase = B_l + (size_t)((kk * 4 + q) * 128 + wc * 64 + rr) * 8;
#pragma unroll
            for (int i = 0; i < 4; ++i) a[i] = *reinterpret_cast<const short8*>(abase + i * 16 * 8);
#pragma unroll
            for (int j = 0; j < 4; ++j) b[j] = *reinterpret_cast<const short8*>(bbase + j * 16 * 8);
#pragma unroll
            for (int i = 0; i < 4; ++i)
#pragma unroll
                for (int j = 0; j < 4; ++j) acc[i][j] = mfma16(a[i], b[j], acc[i][j]);
        }
        __syncthreads();
    }

    int rb = wr * 64 + q * 4;
    int hb = cb + wc * 64 + rr;
#pragma unroll
    for (int i = 0; i < 4; ++i) {
#pragma unroll
        for (int r = 0; r < 4; ++r) {
            int lrow = rb + i * 16 + r;
            int grow = tm * 128 + lrow;
            if (grow < cnt) {
                int p = off + grow;
                int tok = perm_token[p];
                float gate = perm_gate[p];
#pragma unroll
                for (int j = 0; j < 4; ++j)
                    atomicAdd(&out[(size_t)tok * HID_DIM + hb + j * 16], acc[i][j][r] * gate);
            }
        }
    }
}

extern "C" void kernel_launch(void* const* d_in, const int* in_sizes, int n_in,
                              void* d_out, int out_size, void* d_ws, size_t ws_size,
                              hipStream_t stream) {
    const float* x  = (const float*)d_in[0];
    const float* gw = (const float*)d_in[1];
    const float* w1 = (const float*)d_in[2];
    const float* w2 = (const float*)d_in[3];
    const float* w3 = (const float*)d_in[4];
    float* out = (float*)d_out;

    char* ws = (char*)d_ws;
    int*   ctl        = (int*)ws;                          // 256 B control @ 0
    int*   topk_e     = (int*)(ws + 4096);
    float* topk_w     = (float*)(ws + 4096 + 16384);
    int*   perm_token = (int*)(ws + 4096 + 2 * 16384);
    float* perm_gate  = (float*)(ws + 4096 + 3 * 16384);
    unsigned short* xb  = (unsigned short*)(ws + (1u << 20));                 // 4 MB @ 1MB
    unsigned short* hid = (unsigned short*)(ws + 5242880);                    // 29.36 MB
    unsigned short* w1b = (unsigned short*)(ws + 34603008);                   // 58.7 MB
    unsigned short* w2b = (unsigned short*)(ws + 93323264);                   // 58.7 MB
    unsigned short* w3b = (unsigned short*)(ws + 152043520);                  // 58.7 MB (end ~210.8 MB)

    hipMemsetAsync(ctl, 0, 256, stream);
    hipMemsetAsync(out, 0, (size_t)out_size * sizeof(float), stream);

    cvt_k<<<dim3(3584, 1, 3), 256, 0, stream>>>(w1, w2, w3, w1b, w2b, w3b);
    router_k<<<dim3(T_TOKENS / 4), 256, 0, stream>>>(x, gw, xb, topk_e, topk_w, ctl);
    prefix_k<<<dim3(1), 64, 0, stream>>>(ctl);
    scatter_k<<<dim3(T_TOKENS / 256), 256, 0, stream>>>(topk_e, topk_w, ctl, perm_token, perm_gate);
    gemm1_k<<<dim3(16, INTER / 64, NEXP), 256, 0, stream>>>(xb, w1b, w3b, ctl, perm_token, hid);
    gemm2_k<<<dim3(16, HID_DIM / 128, NEXP), 256, 0, stream>>>(hid, w2b, ctl, perm_token, perm_gate, out);
}

// Round 3
// 484.063 us; speedup vs baseline: 2.0051x; 2.0051x over previous
//
#include <hip/hip_runtime.h>
#include <hip/hip_bf16.h>
#include <stdint.h>

#define T_TOKENS 2048
#define HID_DIM 1024
#define INTER 3584
#define NEXP 8
#define PTILES 40   // max padded row-tiles: 4096/128 + 8 alignment pads

typedef float f32x4 __attribute__((ext_vector_type(4)));
typedef short short8 __attribute__((ext_vector_type(8)));
typedef unsigned short ushort8 __attribute__((ext_vector_type(8)));
typedef unsigned short ushort_t;

#define AS1 __attribute__((address_space(1)))
#define AS3 __attribute__((address_space(3)))

__device__ __forceinline__ void gload_lds16(const void* g, void* l) {
    __builtin_amdgcn_global_load_lds((AS1 void*)g, (AS3 void*)l, 16, 0, 0);
}

__device__ __forceinline__ f32x4 mfma16(short8 a, short8 b, f32x4 c) {
    return __builtin_amdgcn_mfma_f32_16x16x32_bf16(a, b, c, 0, 0, 0);
}

__device__ __forceinline__ unsigned short f2bf(float f) {
    union { __hip_bfloat16 h; unsigned short u; } cv;
    cv.h = __float2bfloat16(f);
    return cv.u;
}

__device__ __forceinline__ ushort8 cvt8(float4 v0, float4 v1) {
    ushort8 u;
    u[0] = f2bf(v0.x); u[1] = f2bf(v0.y); u[2] = f2bf(v0.z); u[3] = f2bf(v0.w);
    u[4] = f2bf(v1.x); u[5] = f2bf(v1.y); u[6] = f2bf(v1.z); u[7] = f2bf(v1.w);
    return u;
}

// ---- pack weights fp32 -> bf16 in GEMM tile layout [e][nt][kt][kb8][col64][8] ----
// block = (nt, e, which). thread: col = tid&63, kq = tid>>2? -> kq = tid>>6 (k-quarter, 16 floats)
__global__ __launch_bounds__(256) void pack_w_k(const float* __restrict__ w1, const float* __restrict__ w2,
                                                const float* __restrict__ w3,
                                                unsigned short* __restrict__ w1p,
                                                unsigned short* __restrict__ w3p,
                                                unsigned short* __restrict__ w2p) {
    int which = blockIdx.z;   // 0:w1 1:w3 2:w2
    int e = blockIdx.y;
    int nt = blockIdx.x;
    const float* src;
    unsigned short* dst;
    int R, K;
    if (which == 0) { src = w1; dst = w1p; R = INTER; K = HID_DIM; }
    else if (which == 1) { src = w3; dst = w3p; R = INTER; K = HID_DIM; }
    else { src = w2; dst = w2p; R = HID_DIM; K = INTER; }
    int NT = R >> 6, KT = K >> 6;
    if (nt >= NT) return;

    int col = threadIdx.x & 63;
    int kq = threadIdx.x >> 6;  // 0..3
    const float* s = src + ((size_t)e * R + nt * 64 + col) * K + kq * 16;
    unsigned short* d = dst + ((size_t)(e * NT + nt) * KT) * 4096;

    for (int kt = 0; kt < KT; ++kt) {
        const float* sp = s + kt * 64;
        float4 v0 = *reinterpret_cast<const float4*>(sp);
        float4 v1 = *reinterpret_cast<const float4*>(sp + 4);
        float4 v2 = *reinterpret_cast<const float4*>(sp + 8);
        float4 v3 = *reinterpret_cast<const float4*>(sp + 12);
        unsigned short* dp = d + (size_t)kt * 4096;
        *reinterpret_cast<ushort8*>(dp + ((kq * 2 + 0) * 64 + col) * 8) = cvt8(v0, v1);
        *reinterpret_cast<ushort8*>(dp + ((kq * 2 + 1) * 64 + col) * 8) = cvt8(v2, v3);
    }
}

// ---------------- router: fp32 logits, top-2, renorm weights, per-expert counts ----------------
__global__ void router_k(const float* __restrict__ x, const float* __restrict__ gw,
                         int* __restrict__ topk_e, float* __restrict__ topk_w,
                         int* __restrict__ ctl) {
    int lane = threadIdx.x & 63;
    int wid = threadIdx.x >> 6;
    int t = blockIdx.x * 4 + wid;
    const float* xr = x + (size_t)t * HID_DIM;

    float acc[NEXP];
#pragma unroll
    for (int e = 0; e < NEXP; ++e) acc[e] = 0.f;

#pragma unroll
    for (int j = 0; j < 4; ++j) {
        int c = j * 256 + lane * 4;
        float4 v = *reinterpret_cast<const float4*>(xr + c);
#pragma unroll
        for (int e = 0; e < NEXP; ++e) {
            float4 g = *reinterpret_cast<const float4*>(gw + e * HID_DIM + c);
            acc[e] += v.x * g.x + v.y * g.y + v.z * g.z + v.w * g.w;
        }
    }
#pragma unroll
    for (int off = 32; off > 0; off >>= 1)
#pragma unroll
        for (int e = 0; e < NEXP; ++e) acc[e] += __shfl_xor(acc[e], off, 64);

    if (lane == 0) {
        int e0 = 0;
#pragma unroll
        for (int e = 1; e < NEXP; ++e) if (acc[e] > acc[e0]) e0 = e;
        int e1 = -1;
        float b1 = 0.f;
#pragma unroll
        for (int e = 0; e < NEXP; ++e) {
            if (e == e0) continue;
            if (e1 < 0 || acc[e] > b1) { e1 = e; b1 = acc[e]; }
        }
        float p1 = __expf(b1 - acc[e0]);
        float s = 1.f + p1;
        topk_e[2 * t] = e0; topk_e[2 * t + 1] = e1;
        topk_w[2 * t] = 1.f / s; topk_w[2 * t + 1] = p1 / s;
        atomicAdd(&ctl[e0], 1);
        atomicAdd(&ctl[e1], 1);
    }
}

// ctl: [0..8) counts, [16..24) cursors, [32..40) 128-ALIGNED offsets
__global__ void prefix_k(int* __restrict__ ctl) {
    if (threadIdx.x == 0) {
        int r = 0;
        for (int e = 0; e < NEXP; ++e) {
            ctl[32 + e] = r;
            r += (ctl[e] + 127) & ~127;
            ctl[16 + e] = 0;
        }
    }
}

__global__ void scatter_k(const int* __restrict__ topk_e, const float* __restrict__ topk_w,
                          int* __restrict__ ctl, int* __restrict__ perm_token,
                          float* __restrict__ perm_gate) {
    int t = blockIdx.x * 256 + threadIdx.x;
    if (t >= T_TOKENS) return;
#pragma unroll
    for (int k = 0; k < 2; ++k) {
        int e = topk_e[2 * t + k];
        int p = ctl[32 + e] + atomicAdd(&ctl[16 + e], 1);
        perm_token[p] = t;
        perm_gate[p] = topk_w[2 * t + k];
    }
}

// ---- gather routed tokens into packed A layout [ptile][kt16][kb8][row128][8], fp32->bf16 ----
__global__ __launch_bounds__(256) void pack_x_k(const float* __restrict__ x,
                                                const int* __restrict__ perm_token,
                                                unsigned short* __restrict__ xgp) {
    int ptile = blockIdx.x;
    int row = threadIdx.x & 127;
    int kh = threadIdx.x >> 7;  // 0..1 (half of K)
    int tok = perm_token[ptile * 128 + row];
    const float* s = x + (size_t)tok * HID_DIM + kh * 512;
    unsigned short* d = xgp + (size_t)ptile * 131072;
#pragma unroll
    for (int kt2 = 0; kt2 < 8; ++kt2) {
        int kt = kh * 8 + kt2;
#pragma unroll
        for (int kb = 0; kb < 8; ++kb) {
            float4 v0 = *reinterpret_cast<const float4*>(s + kt2 * 64 + kb * 8);
            float4 v1 = *reinterpret_cast<const float4*>(s + kt2 * 64 + kb * 8 + 4);
            *reinterpret_cast<ushort8*>(d + (size_t)kt * 8192 + (kb * 128 + row) * 8) = cvt8(v0, v1);
        }
    }
}

// ---------------- GEMM1: hid = silu(Xg@w1^T)*(Xg@w3^T). BM=128 BN=64(x2) BK=64 ----------------
// All staging = identity copy of contiguous packed slabs via global_load_lds (lane-linear).
__global__ __launch_bounds__(256) void gemm1_k(
    const unsigned short* __restrict__ xgp,
    const unsigned short* __restrict__ w1p, const unsigned short* __restrict__ w3p,
    const int* __restrict__ ctl, unsigned short* __restrict__ hidp) {
    int e = blockIdx.z;
    int cnt = ctl[e];
    int tm = blockIdx.x;
    if (tm * 128 >= cnt) return;
    int off = ctl[32 + e];
    int nt = blockIdx.y;
    int ptile = (off >> 7) + tm;

    __shared__ __attribute__((aligned(16))) unsigned short A_l[8192];   // [kb8][row128][8] 16KB
    __shared__ __attribute__((aligned(16))) unsigned short B1_l[4096];  // [kb8][col64][8] 8KB
    __shared__ __attribute__((aligned(16))) unsigned short B3_l[4096];

    int tid = threadIdx.x;
    int lane = tid & 63;
    int wid = tid >> 6;
    int wr = wid >> 1, wc = wid & 1;
    int q = lane >> 4, rr = lane & 15;

    const unsigned short* asrc = xgp + (size_t)ptile * 131072;
    const unsigned short* b1s = w1p + (size_t)(e * 56 + nt) * 65536;
    const unsigned short* b3s = w3p + (size_t)(e * 56 + nt) * 65536;

    f32x4 acc1[4][2], acc3[4][2];
#pragma unroll
    for (int i = 0; i < 4; ++i)
#pragma unroll
        for (int j = 0; j < 2; ++j) { acc1[i][j] = 0.f; acc3[i][j] = 0.f; }

    for (int kt = 0; kt < 16; ++kt) {
        const unsigned short* as = asrc + (size_t)kt * 8192;
        const unsigned short* b1 = b1s + (size_t)kt * 4096;
        const unsigned short* b3 = b3s + (size_t)kt * 4096;
#pragma unroll
        for (int c = 0; c < 4; ++c)
            gload_lds16(as + (c * 256 + tid) * 8, A_l + (c * 256 + tid) * 8);
#pragma unroll
        for (int c = 0; c < 2; ++c) {
            gload_lds16(b1 + (c * 256 + tid) * 8, B1_l + (c * 256 + tid) * 8);
            gload_lds16(b3 + (c * 256 + tid) * 8, B3_l + (c * 256 + tid) * 8);
        }
        __syncthreads();
#pragma unroll
        for (int kk = 0; kk < 2; ++kk) {
            short8 a[4], b1v[2], b3v[2];
            const unsigned short* abase = A_l + (size_t)((kk * 4 + q) * 128 + wr * 64 + rr) * 8;
#pragma unroll
            for (int i = 0; i < 4; ++i) a[i] = *reinterpret_cast<const short8*>(abase + i * 16 * 8);
            const unsigned short* b1base = B1_l + (size_t)((kk * 4 + q) * 64 + wc * 32 + rr) * 8;
            const unsigned short* b3base = B3_l + (size_t)((kk * 4 + q) * 64 + wc * 32 + rr) * 8;
#pragma unroll
            for (int j = 0; j < 2; ++j) {
                b1v[j] = *reinterpret_cast<const short8*>(b1base + j * 16 * 8);
                b3v[j] = *reinterpret_cast<const short8*>(b3base + j * 16 * 8);
            }
#pragma unroll
            for (int i = 0; i < 4; ++i)
#pragma unroll
                for (int j = 0; j < 2; ++j) {
                    acc1[i][j] = mfma16(a[i], b1v[j], acc1[i][j]);
                    acc3[i][j] = mfma16(a[i], b3v[j], acc3[i][j]);
                }
        }
        __syncthreads();
    }

    // epilogue: silu(g)*u -> packed hid tile [ptile][nt(kt-dim)][kb][row][8]
    int rbase = wr * 64 + q * 4;
    int colb = wc * 32 + rr;
    unsigned short* hb = hidp + (size_t)(ptile * 56 + nt) * 8192;
#pragma unroll
    for (int i = 0; i < 4; ++i) {
#pragma unroll
        for (int r = 0; r < 4; ++r) {
            int lrow = rbase + i * 16 + r;
            if (tm * 128 + lrow < cnt) {
#pragma unroll
                for (int j = 0; j < 2; ++j) {
                    int col = colb + j * 16;
                    float g = acc1[i][j][r];
                    float u = acc3[i][j][r];
                    float h = (g / (1.f + __expf(-g))) * u;
                    hb[((col >> 3) * 128 + lrow) * 8 + (col & 7)] = f2bf(h);
                }
            }
        }
    }
}

// ---------------- GEMM2: out[tok] += gate*(hid @ w2^T). BM=128 BN=128 BK=64 ----------------
__global__ __launch_bounds__(256) void gemm2_k(
    const unsigned short* __restrict__ hidp, const unsigned short* __restrict__ w2p,
    const int* __restrict__ ctl, const int* __restrict__ perm_token,
    const float* __restrict__ perm_gate, float* __restrict__ out) {
    int e = blockIdx.z;
    int cnt = ctl[e];
    int tm = blockIdx.x;
    if (tm * 128 >= cnt) return;
    int off = ctl[32 + e];
    int ptile = (off >> 7) + tm;

    __shared__ __attribute__((aligned(16))) unsigned short A_l[8192]; // [kb8][row128][8] 16KB
    __shared__ __attribute__((aligned(16))) unsigned short B_l[8192]; // 2 halves of [kb8][col64][8]

    int tid = threadIdx.x;
    int lane = tid & 63;
    int wid = tid >> 6;
    int wr = wid >> 1, wc = wid & 1;
    int q = lane >> 4, rr = lane & 15;

    const unsigned short* asrc = hidp + (size_t)(ptile * 56) * 8192;
    const unsigned short* bs0 = w2p + (size_t)(e * 16 + 2 * blockIdx.y) * 229376;
    const unsigned short* bs1 = bs0 + 229376;

    f32x4 acc[4][4];
#pragma unroll
    for (int i = 0; i < 4; ++i)
#pragma unroll
        for (int j = 0; j < 4; ++j) acc[i][j] = 0.f;

    for (int kt = 0; kt < 56; ++kt) {
        const unsigned short* as = asrc + (size_t)kt * 8192;
        const unsigned short* b0 = bs0 + (size_t)kt * 4096;
        const unsigned short* b1 = bs1 + (size_t)kt * 4096;
#pragma unroll
        for (int c = 0; c < 4; ++c)
            gload_lds16(as + (c * 256 + tid) * 8, A_l + (c * 256 + tid) * 8);
#pragma unroll
        for (int c = 0; c < 2; ++c) {
            gload_lds16(b0 + (c * 256 + tid) * 8, B_l + (c * 256 + tid) * 8);
            gload_lds16(b1 + (c * 256 + tid) * 8, B_l + 4096 + (c * 256 + tid) * 8);
        }
        __syncthreads();
#pragma unroll
        for (int kk = 0; kk < 2; ++kk) {
            short8 a[4], b[4];
            const unsigned short* abase = A_l + (size_t)((kk * 4 + q) * 128 + wr * 64 + rr) * 8;
            const unsigned short* bbase = B_l + (size_t)(wc * 4096) + (size_t)((kk * 4 + q) * 64 + rr) * 8;
#pragma unroll
            for (int i = 0; i < 4; ++i) a[i] = *reinterpret_cast<const short8*>(abase + i * 16 * 8);
#pragma unroll
            for (int j = 0; j < 4; ++j) b[j] = *reinterpret_cast<const short8*>(bbase + j * 16 * 8);
#pragma unroll
            for (int i = 0; i < 4; ++i)
#pragma unroll
                for (int j = 0; j < 4; ++j) acc[i][j] = mfma16(a[i], b[j], acc[i][j]);
        }
        __syncthreads();
    }

    int rb = wr * 64 + q * 4;
    int hb = blockIdx.y * 128 + wc * 64 + rr;
#pragma unroll
    for (int i = 0; i < 4; ++i) {
#pragma unroll
        for (int r = 0; r < 4; ++r) {
            int lrow = rb + i * 16 + r;
            int grow = tm * 128 + lrow;
            if (grow < cnt) {
                int p = off + grow;
                int tok = perm_token[p];
                float gate = perm_gate[p];
#pragma unroll
                for (int j = 0; j < 4; ++j)
                    atomicAdd(&out[(size_t)tok * HID_DIM + hb + j * 16], acc[i][j][r] * gate);
            }
        }
    }
}

extern "C" void kernel_launch(void* const* d_in, const int* in_sizes, int n_in,
                              void* d_out, int out_size, void* d_ws, size_t ws_size,
                              hipStream_t stream) {
    const float* x  = (const float*)d_in[0];
    const float* gw = (const float*)d_in[1];
    const float* w1 = (const float*)d_in[2];
    const float* w2 = (const float*)d_in[3];
    const float* w3 = (const float*)d_in[4];
    float* out = (float*)d_out;

    char* ws = (char*)d_ws;
    int*   ctl        = (int*)ws;                              // 4KB
    int*   topk_e     = (int*)(ws + 4096);                     // 16KB
    float* topk_w     = (float*)(ws + 20480);                  // 16KB
    int*   perm_token = (int*)(ws + 36864);                    // 20KB (5120)
    float* perm_gate  = (float*)(ws + 57344);                  // 20KB
    unsigned short* xgp  = (unsigned short*)(ws + (1ull << 20));        // 10.49MB @1MB
    unsigned short* hidp = (unsigned short*)(ws + 12582912);            // 36.7MB @12MB
    unsigned short* w1p  = (unsigned short*)(ws + 52428800);            // 58.7MB @50MB
    unsigned short* w3p  = (unsigned short*)(ws + 111149056);           // 58.7MB
    unsigned short* w2p  = (unsigned short*)(ws + 169869312);           // 58.7MB (end ~218MB)

    hipMemsetAsync(ctl, 0, 256, stream);
    hipMemsetAsync(perm_token, 0, PTILES * 128 * sizeof(int), stream);
    hipMemsetAsync(out, 0, (size_t)out_size * sizeof(float), stream);

    pack_w_k<<<dim3(56, NEXP, 3), 256, 0, stream>>>(w1, w2, w3, w1p, w3p, w2p);
    router_k<<<dim3(T_TOKENS / 4), 256, 0, stream>>>(x, gw, topk_e, topk_w, ctl);
    prefix_k<<<dim3(1), 64, 0, stream>>>(ctl);
    scatter_k<<<dim3(T_TOKENS / 256), 256, 0, stream>>>(topk_e, topk_w, ctl, perm_token, perm_gate);
    pack_x_k<<<dim3(PTILES), 256, 0, stream>>>(x, perm_token, xgp);
    gemm1_k<<<dim3(PTILES, INTER / 64, NEXP), 256, 0, stream>>>(xgp, w1p, w3p, ctl, hidp);
    gemm2_k<<<dim3(PTILES, HID_DIM / 128, NEXP), 256, 0, stream>>>(hidp, w2p, ctl, perm_token, perm_gate, out);
}

// Round 4
// 421.751 us; speedup vs baseline: 2.3013x; 1.1477x over previous
//
#include <hip/hip_runtime.h>
#include <hip/hip_bf16.h>
#include <stdint.h>

#define T_TOKENS 2048
#define HID_DIM 1024
#define INTER 3584
#define NEXP 8
#define PTILES 40   // max padded row-tiles: 4096/128 + 8 alignment pads

typedef float f32x4 __attribute__((ext_vector_type(4)));
typedef short short8 __attribute__((ext_vector_type(8)));
typedef unsigned short ushort8 __attribute__((ext_vector_type(8)));

#define AS1 __attribute__((address_space(1)))
#define AS3 __attribute__((address_space(3)))

__device__ __forceinline__ void gload_lds16(const void* g, void* l) {
    __builtin_amdgcn_global_load_lds((AS1 void*)g, (AS3 void*)l, 16, 0, 0);
}

__device__ __forceinline__ f32x4 mfma16(short8 a, short8 b, f32x4 c) {
    return __builtin_amdgcn_mfma_f32_16x16x32_bf16(a, b, c, 0, 0, 0);
}

__device__ __forceinline__ unsigned short f2bf(float f) {
    union { __hip_bfloat16 h; unsigned short u; } cv;
    cv.h = __float2bfloat16(f);
    return cv.u;
}

__device__ __forceinline__ ushort8 cvt8(float4 v0, float4 v1) {
    ushort8 u;
    u[0] = f2bf(v0.x); u[1] = f2bf(v0.y); u[2] = f2bf(v0.z); u[3] = f2bf(v0.w);
    u[4] = f2bf(v1.x); u[5] = f2bf(v1.y); u[6] = f2bf(v1.z); u[7] = f2bf(v1.w);
    return u;
}

// ---- pack weights fp32 -> bf16 in GEMM tile layout [e][nt][kt][kb8][col64][8] ----
// ONE 64x64 tile per block: grid (NT*KT=896, NEXP, 3). No inner loop -> max memory parallelism.
__global__ __launch_bounds__(256) void pack_w_k(const float* __restrict__ w1, const float* __restrict__ w2,
                                                const float* __restrict__ w3,
                                                unsigned short* __restrict__ w1p,
                                                unsigned short* __restrict__ w3p,
                                                unsigned short* __restrict__ w2p) {
    int which = blockIdx.z;   // 0:w1 1:w3 2:w2
    int e = blockIdx.y;
    const float* src;
    unsigned short* dst;
    int NT, KT, K;
    if (which == 0) { src = w1; dst = w1p; NT = 56; KT = 16; K = HID_DIM; }
    else if (which == 1) { src = w3; dst = w3p; NT = 56; KT = 16; K = HID_DIM; }
    else { src = w2; dst = w2p; NT = 16; KT = 56; K = INTER; }
    int nt = blockIdx.x % NT;
    int kt = blockIdx.x / NT;

    int col = threadIdx.x & 63;
    int kq = threadIdx.x >> 6;  // 0..3: 16 floats each
    const float* s = src + ((size_t)(e * (NT * 64) + nt * 64 + col)) * K + kt * 64 + kq * 16;
    float4 v0 = *reinterpret_cast<const float4*>(s);
    float4 v1 = *reinterpret_cast<const float4*>(s + 4);
    float4 v2 = *reinterpret_cast<const float4*>(s + 8);
    float4 v3 = *reinterpret_cast<const float4*>(s + 12);
    unsigned short* d = dst + ((size_t)(e * NT + nt) * KT + kt) * 4096;
    *reinterpret_cast<ushort8*>(d + ((kq * 2 + 0) * 64 + col) * 8) = cvt8(v0, v1);
    *reinterpret_cast<ushort8*>(d + ((kq * 2 + 1) * 64 + col) * 8) = cvt8(v2, v3);
}

// ---------------- router: fp32 logits, top-2, renorm weights, per-expert counts ----------------
__global__ void router_k(const float* __restrict__ x, const float* __restrict__ gw,
                         int* __restrict__ topk_e, float* __restrict__ topk_w,
                         int* __restrict__ ctl) {
    int lane = threadIdx.x & 63;
    int wid = threadIdx.x >> 6;
    int t = blockIdx.x * 4 + wid;
    const float* xr = x + (size_t)t * HID_DIM;

    float acc[NEXP];
#pragma unroll
    for (int e = 0; e < NEXP; ++e) acc[e] = 0.f;

#pragma unroll
    for (int j = 0; j < 4; ++j) {
        int c = j * 256 + lane * 4;
        float4 v = *reinterpret_cast<const float4*>(xr + c);
#pragma unroll
        for (int e = 0; e < NEXP; ++e) {
            float4 g = *reinterpret_cast<const float4*>(gw + e * HID_DIM + c);
            acc[e] += v.x * g.x + v.y * g.y + v.z * g.z + v.w * g.w;
        }
    }
#pragma unroll
    for (int off = 32; off > 0; off >>= 1)
#pragma unroll
        for (int e = 0; e < NEXP; ++e) acc[e] += __shfl_xor(acc[e], off, 64);

    if (lane == 0) {
        int e0 = 0;
#pragma unroll
        for (int e = 1; e < NEXP; ++e) if (acc[e] > acc[e0]) e0 = e;
        int e1 = -1;
        float b1 = 0.f;
#pragma unroll
        for (int e = 0; e < NEXP; ++e) {
            if (e == e0) continue;
            if (e1 < 0 || acc[e] > b1) { e1 = e; b1 = acc[e]; }
        }
        float p1 = __expf(b1 - acc[e0]);
        float s = 1.f + p1;
        topk_e[2 * t] = e0; topk_e[2 * t + 1] = e1;
        topk_w[2 * t] = 1.f / s; topk_w[2 * t + 1] = p1 / s;
        atomicAdd(&ctl[e0], 1);
        atomicAdd(&ctl[e1], 1);
    }
}

// ctl: [0..8) counts, [16..24) cursors, [32..40) 128-ALIGNED offsets
__global__ void prefix_k(int* __restrict__ ctl) {
    if (threadIdx.x == 0) {
        int r = 0;
        for (int e = 0; e < NEXP; ++e) {
            ctl[32 + e] = r;
            r += (ctl[e] + 127) & ~127;
            ctl[16 + e] = 0;
        }
    }
}

__global__ void scatter_k(const int* __restrict__ topk_e, const float* __restrict__ topk_w,
                          int* __restrict__ ctl, int* __restrict__ perm_token,
                          float* __restrict__ perm_gate) {
    int t = blockIdx.x * 256 + threadIdx.x;
    if (t >= T_TOKENS) return;
#pragma unroll
    for (int k = 0; k < 2; ++k) {
        int e = topk_e[2 * t + k];
        int p = ctl[32 + e] + atomicAdd(&ctl[16 + e], 1);
        perm_token[p] = t;
        perm_gate[p] = topk_w[2 * t + k];
    }
}

// ---- gather routed tokens into packed A layout [ptile][kt16][kb8][row128][8], fp32->bf16 ----
// grid (PTILES, 16): one (ptile, kt) per block.
__global__ __launch_bounds__(256) void pack_x_k(const float* __restrict__ x,
                                                const int* __restrict__ perm_token,
                                                unsigned short* __restrict__ xgp) {
    int ptile = blockIdx.x;
    int kt = blockIdx.y;
    int row = threadIdx.x & 127;
    int kh = threadIdx.x >> 7;  // 0..1: 32 k each (4 kb)
    int tok = perm_token[ptile * 128 + row];
    const float* s = x + (size_t)tok * HID_DIM + kt * 64 + kh * 32;
    unsigned short* d = xgp + (size_t)ptile * 131072 + (size_t)kt * 8192;
#pragma unroll
    for (int kb2 = 0; kb2 < 4; ++kb2) {
        int kb = kh * 4 + kb2;
        float4 v0 = *reinterpret_cast<const float4*>(s + kb2 * 8);
        float4 v1 = *reinterpret_cast<const float4*>(s + kb2 * 8 + 4);
        *reinterpret_cast<ushort8*>(d + (kb * 128 + row) * 8) = cvt8(v0, v1);
    }
}

// ---------------- GEMM1: hid = silu(Xg@w1^T)*(Xg@w3^T). BM=128 BN=64(x2) BK=64 ----------------
// All staging = identity copy of contiguous packed slabs via global_load_lds (lane-linear).
__global__ __launch_bounds__(256) void gemm1_k(
    const unsigned short* __restrict__ xgp,
    const unsigned short* __restrict__ w1p, const unsigned short* __restrict__ w3p,
    const int* __restrict__ ctl, unsigned short* __restrict__ hidp) {
    int e = blockIdx.z;
    int cnt = ctl[e];
    int tm = blockIdx.x;
    if (tm * 128 >= cnt) return;
    int off = ctl[32 + e];
    int nt = blockIdx.y;
    int ptile = (off >> 7) + tm;

    __shared__ __attribute__((aligned(16))) unsigned short A_l[8192];   // [kb8][row128][8] 16KB
    __shared__ __attribute__((aligned(16))) unsigned short B1_l[4096];  // [kb8][col64][8] 8KB
    __shared__ __attribute__((aligned(16))) unsigned short B3_l[4096];

    int tid = threadIdx.x;
    int lane = tid & 63;
    int wid = tid >> 6;
    int wr = wid >> 1, wc = wid & 1;
    int q = lane >> 4, rr = lane & 15;

    const unsigned short* asrc = xgp + (size_t)ptile * 131072;
    const unsigned short* b1s = w1p + (size_t)(e * 56 + nt) * 65536;
    const unsigned short* b3s = w3p + (size_t)(e * 56 + nt) * 65536;

    f32x4 acc1[4][2], acc3[4][2];
#pragma unroll
    for (int i = 0; i < 4; ++i)
#pragma unroll
        for (int j = 0; j < 2; ++j) { acc1[i][j] = 0.f; acc3[i][j] = 0.f; }

    for (int kt = 0; kt < 16; ++kt) {
        const unsigned short* as = asrc + (size_t)kt * 8192;
        const unsigned short* b1 = b1s + (size_t)kt * 4096;
        const unsigned short* b3 = b3s + (size_t)kt * 4096;
#pragma unroll
        for (int c = 0; c < 4; ++c)
            gload_lds16(as + (c * 256 + tid) * 8, A_l + (c * 256 + tid) * 8);
#pragma unroll
        for (int c = 0; c < 2; ++c) {
            gload_lds16(b1 + (c * 256 + tid) * 8, B1_l + (c * 256 + tid) * 8);
            gload_lds16(b3 + (c * 256 + tid) * 8, B3_l + (c * 256 + tid) * 8);
        }
        __syncthreads();
#pragma unroll
        for (int kk = 0; kk < 2; ++kk) {
            short8 a[4], b1v[2], b3v[2];
            const unsigned short* abase = A_l + (size_t)((kk * 4 + q) * 128 + wr * 64 + rr) * 8;
#pragma unroll
            for (int i = 0; i < 4; ++i) a[i] = *reinterpret_cast<const short8*>(abase + i * 16 * 8);
            const unsigned short* b1base = B1_l + (size_t)((kk * 4 + q) * 64 + wc * 32 + rr) * 8;
            const unsigned short* b3base = B3_l + (size_t)((kk * 4 + q) * 64 + wc * 32 + rr) * 8;
#pragma unroll
            for (int j = 0; j < 2; ++j) {
                b1v[j] = *reinterpret_cast<const short8*>(b1base + j * 16 * 8);
                b3v[j] = *reinterpret_cast<const short8*>(b3base + j * 16 * 8);
            }
#pragma unroll
            for (int i = 0; i < 4; ++i)
#pragma unroll
                for (int j = 0; j < 2; ++j) {
                    acc1[i][j] = mfma16(a[i], b1v[j], acc1[i][j]);
                    acc3[i][j] = mfma16(a[i], b3v[j], acc3[i][j]);
                }
        }
        __syncthreads();
    }

    // epilogue: silu(g)*u -> packed hid tile [ptile][nt(kt-dim)][kb][row][8]
    int rbase = wr * 64 + q * 4;
    int colb = wc * 32 + rr;
    unsigned short* hb = hidp + (size_t)(ptile * 56 + nt) * 8192;
#pragma unroll
    for (int i = 0; i < 4; ++i) {
#pragma unroll
        for (int r = 0; r < 4; ++r) {
            int lrow = rbase + i * 16 + r;
            if (tm * 128 + lrow < cnt) {
#pragma unroll
                for (int j = 0; j < 2; ++j) {
                    int col = colb + j * 16;
                    float g = acc1[i][j][r];
                    float u = acc3[i][j][r];
                    float h = (g / (1.f + __expf(-g))) * u;
                    hb[((col >> 3) * 128 + lrow) * 8 + (col & 7)] = f2bf(h);
                }
            }
        }
    }
}

// ---------------- GEMM2: out[tok] += gate*(hid @ w2^T). BM=128 BN=128 BK=64 ----------------
__global__ __launch_bounds__(256) void gemm2_k(
    const unsigned short* __restrict__ hidp, const unsigned short* __restrict__ w2p,
    const int* __restrict__ ctl, const int* __restrict__ perm_token,
    const float* __restrict__ perm_gate, float* __restrict__ out) {
    int e = blockIdx.z;
    int cnt = ctl[e];
    int tm = blockIdx.x;
    if (tm * 128 >= cnt) return;
    int off = ctl[32 + e];
    int ptile = (off >> 7) + tm;

    __shared__ __attribute__((aligned(16))) unsigned short A_l[8192]; // [kb8][row128][8] 16KB
    __shared__ __attribute__((aligned(16))) unsigned short B_l[8192]; // 2 halves of [kb8][col64][8]

    int tid = threadIdx.x;
    int lane = tid & 63;
    int wid = tid >> 6;
    int wr = wid >> 1, wc = wid & 1;
    int q = lane >> 4, rr = lane & 15;

    const unsigned short* asrc = hidp + (size_t)(ptile * 56) * 8192;
    const unsigned short* bs0 = w2p + (size_t)(e * 16 + 2 * blockIdx.y) * 229376;
    const unsigned short* bs1 = bs0 + 229376;

    f32x4 acc[4][4];
#pragma unroll
    for (int i = 0; i < 4; ++i)
#pragma unroll
        for (int j = 0; j < 4; ++j) acc[i][j] = 0.f;

    for (int kt = 0; kt < 56; ++kt) {
        const unsigned short* as = asrc + (size_t)kt * 8192;
        const unsigned short* b0 = bs0 + (size_t)kt * 4096;
        const unsigned short* b1 = bs1 + (size_t)kt * 4096;
#pragma unroll
        for (int c = 0; c < 4; ++c)
            gload_lds16(as + (c * 256 + tid) * 8, A_l + (c * 256 + tid) * 8);
#pragma unroll
        for (int c = 0; c < 2; ++c) {
            gload_lds16(b0 + (c * 256 + tid) * 8, B_l + (c * 256 + tid) * 8);
            gload_lds16(b1 + (c * 256 + tid) * 8, B_l + 4096 + (c * 256 + tid) * 8);
        }
        __syncthreads();
#pragma unroll
        for (int kk = 0; kk < 2; ++kk) {
            short8 a[4], b[4];
            const unsigned short* abase = A_l + (size_t)((kk * 4 + q) * 128 + wr * 64 + rr) * 8;
            const unsigned short* bbase = B_l + (size_t)(wc * 4096) + (size_t)((kk * 4 + q) * 64 + rr) * 8;
#pragma unroll
            for (int i = 0; i < 4; ++i) a[i] = *reinterpret_cast<const short8*>(abase + i * 16 * 8);
#pragma unroll
            for (int j = 0; j < 4; ++j) b[j] = *reinterpret_cast<const short8*>(bbase + j * 16 * 8);
#pragma unroll
            for (int i = 0; i < 4; ++i)
#pragma unroll
                for (int j = 0; j < 4; ++j) acc[i][j] = mfma16(a[i], b[j], acc[i][j]);
        }
        __syncthreads();
    }

    int rb = wr * 64 + q * 4;
    int hb = blockIdx.y * 128 + wc * 64 + rr;
#pragma unroll
    for (int i = 0; i < 4; ++i) {
#pragma unroll
        for (int r = 0; r < 4; ++r) {
            int lrow = rb + i * 16 + r;
            int grow = tm * 128 + lrow;
            if (grow < cnt) {
                int p = off + grow;
                int tok = perm_token[p];
                float gate = perm_gate[p];
#pragma unroll
                for (int j = 0; j < 4; ++j)
                    atomicAdd(&out[(size_t)tok * HID_DIM + hb + j * 16], acc[i][j][r] * gate);
            }
        }
    }
}

extern "C" void kernel_launch(void* const* d_in, const int* in_sizes, int n_in,
                              void* d_out, int out_size, void* d_ws, size_t ws_size,
                              hipStream_t stream) {
    const float* x  = (const float*)d_in[0];
    const float* gw = (const float*)d_in[1];
    const float* w1 = (const float*)d_in[2];
    const float* w2 = (const float*)d_in[3];
    const float* w3 = (const float*)d_in[4];
    float* out = (float*)d_out;

    char* ws = (char*)d_ws;
    int*   ctl        = (int*)ws;                              // 4KB
    int*   topk_e     = (int*)(ws + 4096);                     // 16KB
    float* topk_w     = (float*)(ws + 20480);                  // 16KB
    int*   perm_token = (int*)(ws + 36864);                    // 20KB (5120)
    float* perm_gate  = (float*)(ws + 57344);                  // 20KB
    unsigned short* xgp  = (unsigned short*)(ws + (1ull << 20));        // 10.49MB @1MB
    unsigned short* hidp = (unsigned short*)(ws + 12582912);            // 36.7MB @12MB
    unsigned short* w1p  = (unsigned short*)(ws + 52428800);            // 58.7MB @50MB
    unsigned short* w3p  = (unsigned short*)(ws + 111149056);           // 58.7MB
    unsigned short* w2p  = (unsigned short*)(ws + 169869312);           // 58.7MB (end ~218MB)

    hipMemsetAsync(ctl, 0, 256, stream);
    hipMemsetAsync(perm_token, 0, PTILES * 128 * sizeof(int), stream);
    hipMemsetAsync(out, 0, (size_t)out_size * sizeof(float), stream);

    pack_w_k<<<dim3(896, NEXP, 3), 256, 0, stream>>>(w1, w2, w3, w1p, w3p, w2p);
    router_k<<<dim3(T_TOKENS / 4), 256, 0, stream>>>(x, gw, topk_e, topk_w, ctl);
    prefix_k<<<dim3(1), 64, 0, stream>>>(ctl);
    scatter_k<<<dim3(T_TOKENS / 256), 256, 0, stream>>>(topk_e, topk_w, ctl, perm_token, perm_gate);
    pack_x_k<<<dim3(PTILES, 16), 256, 0, stream>>>(x, perm_token, xgp);
    gemm1_k<<<dim3(PTILES, INTER / 64, NEXP), 256, 0, stream>>>(xgp, w1p, w3p, ctl, hidp);
    gemm2_k<<<dim3(PTILES, HID_DIM / 128, NEXP), 256, 0, stream>>>(hidp, w2p, ctl, perm_token, perm_gate, out);
}